// Round 9
// baseline (293.409 us; speedup 1.0000x reference)
//
#include <hip/hip_runtime.h>
#include <hip/hip_bf16.h>

// Problem constants (B=2, P=2048, D=768, H=12, hd=64)
#define B_  2
#define P_  2048
#define D_  768
#define H_  12
#define HD_ 64
#define M_  (B_ * P_)   // 4096
#define N1_ (3 * D_)    // 2304

typedef __attribute__((ext_vector_type(8))) short short8;   // 8 bf16 (4 VGPRs)
typedef __attribute__((ext_vector_type(4))) float f32x4;    // MFMA accumulator
typedef unsigned short ushort;

__device__ __forceinline__ ushort f2bf(float f) {
    unsigned u = __float_as_uint(f);
    u += 0x7fffu + ((u >> 16) & 1u);   // RNE
    return (ushort)(u >> 16);
}
__device__ __forceinline__ float bf2f(ushort u) {
    return __uint_as_float((unsigned)u << 16);
}

// ===========================================================================
// Kernel 1: qkv = x @ W_qkv (bf16 MFMA) + fused per-head QK-LayerNorm.
// (unchanged from R7/R8)
// ===========================================================================
__global__ __launch_bounds__(256) void gemm_qkv_mfma(
        const float* __restrict__ x, const float* __restrict__ w,
        const float* __restrict__ qs, const float* __restrict__ qb,
        const float* __restrict__ ks, const float* __restrict__ kb,
        ushort* __restrict__ qkv) {
    __shared__ __align__(16) ushort As[128][40];
    __shared__ __align__(16) ushort Bs[128][40];

    const int tid  = threadIdx.x;
    const int lane = tid & 63;
    const int wv   = tid >> 6;
    const int quad = lane >> 4;
    const int col  = lane & 15;
    const int wr   = (wv >> 1) * 64;
    const int wc   = (wv & 1) * 64;
    const int rowBase = blockIdx.y * 128;
    const int colBase = blockIdx.x * 128;

    const int nB    = tid & 127;
    const int khalf = tid >> 7;
    const int am    = tid >> 3, ac4 = tid & 7;

    float4 apre[4];
    float  bpre[16];

    auto load_tile = [&](int kt) {
        const int k0 = kt * 32;
#pragma unroll
        for (int i = 0; i < 4; i++)
            apre[i] = *(const float4*)(x + (size_t)(rowBase + am + i * 32) * D_ + k0 + ac4 * 4);
#pragma unroll
        for (int j = 0; j < 16; j++)
            bpre[j] = w[(size_t)(k0 + khalf * 16 + j) * N1_ + colBase + nB];
    };

    f32x4 acc[4][4];
#pragma unroll
    for (int i = 0; i < 4; i++)
#pragma unroll
        for (int j = 0; j < 4; j++) acc[i][j] = (f32x4){0.f, 0.f, 0.f, 0.f};

    load_tile(0);
    const int NT = D_ / 32;
    for (int kt = 0; kt < NT; kt++) {
        __syncthreads();
#pragma unroll
        for (int i = 0; i < 4; i++) {
            ushort u4[4] = {f2bf(apre[i].x), f2bf(apre[i].y), f2bf(apre[i].z), f2bf(apre[i].w)};
            *(uint2*)&As[am + i * 32][ac4 * 4] = *(uint2*)u4;
        }
        {
            ushort us[16];
#pragma unroll
            for (int j = 0; j < 16; j++) us[j] = f2bf(bpre[j]);
            *(short8*)&Bs[nB][khalf * 16]     = *(short8*)&us[0];
            *(short8*)&Bs[nB][khalf * 16 + 8] = *(short8*)&us[8];
        }
        __syncthreads();
        if (kt + 1 < NT) load_tile(kt + 1);

        short8 af[4], bf[4];
#pragma unroll
        for (int mt = 0; mt < 4; mt++) af[mt] = *(const short8*)&As[wr + mt * 16 + col][quad * 8];
#pragma unroll
        for (int nt = 0; nt < 4; nt++) bf[nt] = *(const short8*)&Bs[wc + nt * 16 + col][quad * 8];
#pragma unroll
        for (int mt = 0; mt < 4; mt++)
#pragma unroll
            for (int nt = 0; nt < 4; nt++)
                acc[mt][nt] = __builtin_amdgcn_mfma_f32_16x16x32_bf16(af[mt], bf[nt], acc[mt][nt], 0, 0, 0);
    }

    const int comp = colBase / D_;
    const int rem  = colBase + wc - comp * D_;
    const int h    = rem >> 6;
    float sc4[4] = {0, 0, 0, 0}, bi4[4] = {0, 0, 0, 0};
    if (comp == 0) {
#pragma unroll
        for (int nt = 0; nt < 4; nt++) { sc4[nt] = qs[nt * 16 + col]; bi4[nt] = qb[nt * 16 + col]; }
    } else if (comp == 1) {
#pragma unroll
        for (int nt = 0; nt < 4; nt++) { sc4[nt] = ks[nt * 16 + col]; bi4[nt] = kb[nt * 16 + col]; }
    }

#pragma unroll
    for (int mt = 0; mt < 4; mt++) {
#pragma unroll
        for (int r = 0; r < 4; r++) {
            int m  = rowBase + wr + mt * 16 + quad * 4 + r;
            int bb = m >> 11;
            int p  = m & 2047;
            float v0 = acc[mt][0][r], v1 = acc[mt][1][r], v2 = acc[mt][2][r], v3 = acc[mt][3][r];
            if (comp < 2) {
                float s = v0 + v1 + v2 + v3;
#pragma unroll
                for (int off = 1; off < 16; off <<= 1) s += __shfl_xor(s, off, 64);
                float mean = s * (1.0f / 64.0f);
                float d0 = v0 - mean, d1 = v1 - mean, d2 = v2 - mean, d3 = v3 - mean;
                float sq = d0 * d0 + d1 * d1 + d2 * d2 + d3 * d3;
#pragma unroll
                for (int off = 1; off < 16; off <<= 1) sq += __shfl_xor(sq, off, 64);
                float inv = rsqrtf(sq * (1.0f / 64.0f) + 1e-6f);
                v0 = d0 * inv * sc4[0] + bi4[0];
                v1 = d1 * inv * sc4[1] + bi4[1];
                v2 = d2 * inv * sc4[2] + bi4[2];
                v3 = d3 * inv * sc4[3] + bi4[3];
                if (comp == 0) { v0 *= 0.125f; v1 *= 0.125f; v2 *= 0.125f; v3 *= 0.125f; }
            }
            size_t base = ((((size_t)comp * B_ + bb) * H_ + h) * P_ + p) * HD_;
            qkv[base +  0 + col] = f2bf(v0);
            qkv[base + 16 + col] = f2bf(v1);
            qkv[base + 32 + col] = f2bf(v2);
            qkv[base + 48 + col] = f2bf(v3);
        }
    }
}

// ===========================================================================
// Kernel 2: one-time V transpose: [b][h][P][hd] -> [b][h][hd][P].
// Strided gather once per tile (previously re-done by 32 attn blocks).
// ===========================================================================
__global__ __launch_bounds__(256) void transpose_v(const ushort* __restrict__ qkv,
                                                   ushort* __restrict__ v_t) {
    const int p0 = blockIdx.x * 64;
    const int bh = blockIdx.y;
    const int tid = threadIdx.x;
    const int vd = tid & 63, vkh = tid >> 6;

    const ushort* vg = qkv + ((size_t)2 * B_ * H_ + bh) * P_ * HD_;
    ushort us[16];
#pragma unroll
    for (int j = 0; j < 16; j++)
        us[j] = vg[(size_t)(p0 + vkh * 16 + j) * HD_ + vd];
    ushort* dst = v_t + ((size_t)bh * HD_ + vd) * P_ + p0 + vkh * 16;
    *(uint4*)&dst[0] = *(uint4*)&us[0];
    *(uint4*)&dst[8] = *(uint4*)&us[8];
}

// ===========================================================================
// Kernel 3: flash attention (R8 structure: clamped unnormalized softmax),
// V staged from pre-transposed v_t via b128 (same clean pattern as K).
// Epilogue: bf16 output + per-row sum/sumsq atomics for fused downstream LN.
// ===========================================================================
__global__ __launch_bounds__(256) void attn_mfma(const ushort* __restrict__ qkv,
                                                 const ushort* __restrict__ v_t,
                                                 ushort* __restrict__ attn_sb,
                                                 float* __restrict__ stats) {
    const int p0 = blockIdx.x * 64;
    const int bh = blockIdx.y;
    const int b  = bh / H_, h = bh % H_;
    const int tid  = threadIdx.x;
    const int lane = tid & 63;
    const int wv   = tid >> 6;
    const int quad = lane >> 4;
    const int col  = lane & 15;

    __shared__ __align__(16) ushort Qs[64][72];
    __shared__ __align__(16) ushort Ks[64][72];
    __shared__ __align__(16) ushort Vs[64][72];      // [dim][key]
    __shared__ __align__(16) ushort Ps[4][16][72];

    const size_t hs = (size_t)P_ * HD_;
    const ushort* qg  = qkv + ((size_t)(0 * B_ + b) * H_ + h) * hs + (size_t)p0 * HD_;
    const ushort* kg  = qkv + ((size_t)(1 * B_ + b) * H_ + h) * hs;
    const ushort* vtg = v_t + (size_t)bh * HD_ * P_;   // [64][P]

    // Stage Q (64x64 bf16)
#pragma unroll
    for (int i = 0; i < 2; i++) {
        int e = tid + i * 256;
        int r = e >> 3, c8 = e & 7;
        *(uint4*)&Qs[r][c8 * 8] = *(const uint4*)(qg + (size_t)r * HD_ + c8 * 8);
    }
    __syncthreads();
    short8 aq0 = *(const short8*)&Qs[wv * 16 + col][0 * 32 + quad * 8];
    short8 aq1 = *(const short8*)&Qs[wv * 16 + col][1 * 32 + quad * 8];

    float lrow[4] = {0.f, 0.f, 0.f, 0.f};
    f32x4 oacc[4];
#pragma unroll
    for (int nt = 0; nt < 4; nt++) oacc[nt] = (f32x4){0.f, 0.f, 0.f, 0.f};

    const int kr = tid >> 3, kc8 = tid & 7;   // staging coords (both K and V^T)

    uint4 kpre[2], vpre[2];
    auto load_tile = [&](int kt) {
        const ushort* kg_t = kg + (size_t)kt * 64 * HD_;
        kpre[0] = *(const uint4*)(kg_t + (size_t)kr * HD_ + kc8 * 8);
        kpre[1] = *(const uint4*)(kg_t + (size_t)(kr + 32) * HD_ + kc8 * 8);
        const ushort* vt_t = vtg + kt * 64;
        vpre[0] = *(const uint4*)(vt_t + (size_t)kr * P_ + kc8 * 8);
        vpre[1] = *(const uint4*)(vt_t + (size_t)(kr + 32) * P_ + kc8 * 8);
    };

    load_tile(0);
    const int NT = P_ / 64;
    for (int kt = 0; kt < NT; kt++) {
        __syncthreads();
        *(uint4*)&Ks[kr][kc8 * 8]      = kpre[0];
        *(uint4*)&Ks[kr + 32][kc8 * 8] = kpre[1];
        *(uint4*)&Vs[kr][kc8 * 8]      = vpre[0];
        *(uint4*)&Vs[kr + 32][kc8 * 8] = vpre[1];
        __syncthreads();
        if (kt + 1 < NT) load_tile(kt + 1);

        // S = Q @ K^T
        f32x4 s[4];
#pragma unroll
        for (int nt = 0; nt < 4; nt++) {
            s[nt] = (f32x4){0.f, 0.f, 0.f, 0.f};
            short8 b0 = *(const short8*)&Ks[nt * 16 + col][0 * 32 + quad * 8];
            short8 b1 = *(const short8*)&Ks[nt * 16 + col][1 * 32 + quad * 8];
            s[nt] = __builtin_amdgcn_mfma_f32_16x16x32_bf16(aq0, b0, s[nt], 0, 0, 0);
            s[nt] = __builtin_amdgcn_mfma_f32_16x16x32_bf16(aq1, b1, s[nt], 0, 0, 0);
        }

        // Unnormalized clamped softmax
#pragma unroll
        for (int r = 0; r < 4; r++) {
#pragma unroll
            for (int nt = 0; nt < 4; nt++) {
                float p = __expf(fminf(s[nt][r], 60.f));
                lrow[r] += p;
                Ps[wv][quad * 4 + r][nt * 16 + col] = f2bf(p);
            }
        }
        // No barrier: Ps is per-wave; DS ops are wave-in-order.

        // O += P @ V
#pragma unroll
        for (int nt = 0; nt < 4; nt++) {
#pragma unroll
            for (int ks2 = 0; ks2 < 2; ks2++) {
                short8 a   = *(const short8*)&Ps[wv][col][ks2 * 32 + quad * 8];
                short8 bfr = *(const short8*)&Vs[nt * 16 + col][ks2 * 32 + quad * 8];
                oacc[nt] = __builtin_amdgcn_mfma_f32_16x16x32_bf16(a, bfr, oacc[nt], 0, 0, 0);
            }
        }
    }

    // Row-sum reduction (within quad: xor over col bits)
#pragma unroll
    for (int r = 0; r < 4; r++) {
#pragma unroll
        for (int off = 1; off < 16; off <<= 1) lrow[r] += __shfl_xor(lrow[r], off, 64);
    }

    // Writeback bf16 + per-row LN stats (sum, sumsq) via atomics
#pragma unroll
    for (int r = 0; r < 4; r++) {
        float invl = 1.0f / lrow[r];
        int q = p0 + wv * 16 + quad * 4 + r;
        size_t orow = (size_t)(b * P_ + q);
        ushort* dst = attn_sb + orow * D_ + h * HD_;
        float psum = 0.f, psq = 0.f;
#pragma unroll
        for (int nt = 0; nt < 4; nt++) {
            float o = oacc[nt][r] * invl;
            psum += o; psq += o * o;
            dst[nt * 16 + col] = f2bf(o);
        }
#pragma unroll
        for (int off = 1; off < 16; off <<= 1) {
            psum += __shfl_xor(psum, off, 64);
            psq  += __shfl_xor(psq,  off, 64);
        }
        if (col == 0) {
            atomicAdd(&stats[2 * orow],     psum);
            atomicAdd(&stats[2 * orow + 1], psq);
        }
    }
}

// ===========================================================================
// Kernel 4: out = LayerNorm(attn)(applied in staging) @ W_out + b_out.
// A = bf16 attn_sb + per-row stats; LN applied during LDS staging.
// ===========================================================================
__global__ __launch_bounds__(256) void gemm_out_mfma(
        const ushort* __restrict__ a, const float* __restrict__ stats,
        const float* __restrict__ osc, const float* __restrict__ ob,
        const float* __restrict__ w, const float* __restrict__ bias,
        float* __restrict__ out) {
    __shared__ __align__(16) ushort As[128][40];
    __shared__ __align__(16) ushort Bs[128][40];

    const int tid  = threadIdx.x;
    const int lane = tid & 63;
    const int wv   = tid >> 6;
    const int quad = lane >> 4;
    const int col  = lane & 15;
    const int wr   = (wv >> 1) * 64;
    const int wc   = (wv & 1) * 64;
    const int rowBase = blockIdx.y * 128;
    const int colBase = blockIdx.x * 128;

    const int nB    = tid & 127;
    const int khalf = tid >> 7;
    const int am    = tid >> 2, ac8 = tid & 3;

    // Per-row LN stats (rows am, am+64) — loaded once.
    float mean0, rstd0, mean1, rstd1;
    {
        float2 s0 = *(const float2*)&stats[2 * (rowBase + am)];
        float2 s1 = *(const float2*)&stats[2 * (rowBase + am + 64)];
        mean0 = s0.x * (1.0f / 768.0f);
        rstd0 = rsqrtf(s0.y * (1.0f / 768.0f) - mean0 * mean0 + 1e-6f);
        mean1 = s1.x * (1.0f / 768.0f);
        rstd1 = rsqrtf(s1.y * (1.0f / 768.0f) - mean1 * mean1 + 1e-6f);
    }

    uint4 apre[2];
    float oscp[8], obp[8];
    float bpre[16];
    auto load_tile = [&](int kt) {
        const int k0 = kt * 32;
        apre[0] = *(const uint4*)(a + (size_t)(rowBase + am) * D_ + k0 + ac8 * 8);
        apre[1] = *(const uint4*)(a + (size_t)(rowBase + am + 64) * D_ + k0 + ac8 * 8);
        *(float4*)&oscp[0] = *(const float4*)&osc[k0 + ac8 * 8];
        *(float4*)&oscp[4] = *(const float4*)&osc[k0 + ac8 * 8 + 4];
        *(float4*)&obp[0]  = *(const float4*)&ob[k0 + ac8 * 8];
        *(float4*)&obp[4]  = *(const float4*)&ob[k0 + ac8 * 8 + 4];
#pragma unroll
        for (int j = 0; j < 16; j++)
            bpre[j] = w[(size_t)(k0 + khalf * 16 + j) * D_ + colBase + nB];
    };

    f32x4 acc[4][4];
#pragma unroll
    for (int i = 0; i < 4; i++)
#pragma unroll
        for (int j = 0; j < 4; j++) acc[i][j] = (f32x4){0.f, 0.f, 0.f, 0.f};

    load_tile(0);
    const int NT = D_ / 32;
    for (int kt = 0; kt < NT; kt++) {
        __syncthreads();
        {
            const ushort* u0 = (const ushort*)&apre[0];
            const ushort* u1 = (const ushort*)&apre[1];
            ushort o0[8], o1[8];
#pragma unroll
            for (int j = 0; j < 8; j++) {
                o0[j] = f2bf((bf2f(u0[j]) - mean0) * rstd0 * oscp[j] + obp[j]);
                o1[j] = f2bf((bf2f(u1[j]) - mean1) * rstd1 * oscp[j] + obp[j]);
            }
            *(short8*)&As[am][ac8 * 8]      = *(short8*)&o0;
            *(short8*)&As[am + 64][ac8 * 8] = *(short8*)&o1;
        }
        {
            ushort us[16];
#pragma unroll
            for (int j = 0; j < 16; j++) us[j] = f2bf(bpre[j]);
            *(short8*)&Bs[nB][khalf * 16]     = *(short8*)&us[0];
            *(short8*)&Bs[nB][khalf * 16 + 8] = *(short8*)&us[8];
        }
        __syncthreads();
        if (kt + 1 < NT) load_tile(kt + 1);

        short8 af[4], bf[4];
#pragma unroll
        for (int mt = 0; mt < 4; mt++) af[mt] = *(const short8*)&As[wr + mt * 16 + col][quad * 8];
#pragma unroll
        for (int nt = 0; nt < 4; nt++) bf[nt] = *(const short8*)&Bs[wc + nt * 16 + col][quad * 8];
#pragma unroll
        for (int mt = 0; mt < 4; mt++)
#pragma unroll
            for (int nt = 0; nt < 4; nt++)
                acc[mt][nt] = __builtin_amdgcn_mfma_f32_16x16x32_bf16(af[mt], bf[nt], acc[mt][nt], 0, 0, 0);
    }

    float b4[4];
#pragma unroll
    for (int nt = 0; nt < 4; nt++) b4[nt] = bias[colBase + wc + nt * 16 + col];
#pragma unroll
    for (int mt = 0; mt < 4; mt++) {
#pragma unroll
        for (int r = 0; r < 4; r++) {
            int m = rowBase + wr + mt * 16 + quad * 4 + r;
            float* dst = out + (size_t)m * D_ + colBase + wc;
#pragma unroll
            for (int nt = 0; nt < 4; nt++)
                dst[nt * 16 + col] = acc[mt][nt][r] + b4[nt];
        }
    }
}

// ---------------------------------------------------------------------------
extern "C" void kernel_launch(void* const* d_in, const int* in_sizes, int n_in,
                              void* d_out, int out_size, void* d_ws, size_t ws_size,
                              hipStream_t stream) {
    const float* x    = (const float*)d_in[0];
    const float* Wqkv = (const float*)d_in[1];
    const float* qs   = (const float*)d_in[2];
    const float* qb   = (const float*)d_in[3];
    const float* ks   = (const float*)d_in[4];
    const float* kb   = (const float*)d_in[5];
    const float* osc  = (const float*)d_in[6];
    const float* ob   = (const float*)d_in[7];
    const float* Wout = (const float*)d_in[8];
    const float* bout = (const float*)d_in[9];
    float* out = (float*)d_out;

    // Workspace (31.5 MB): qkv bf16 18.9MB | v_t bf16 6.3MB | attn bf16 6.3MB | stats 32KB
    ushort* qkv     = (ushort*)d_ws;
    ushort* v_t     = qkv + (size_t)3 * B_ * H_ * P_ * HD_;
    ushort* attn_sb = v_t + (size_t)B_ * H_ * HD_ * P_;
    float*  stats   = (float*)(attn_sb + (size_t)B_ * P_ * D_);

    hipMemsetAsync(stats, 0, (size_t)M_ * 2 * sizeof(float), stream);
    gemm_qkv_mfma<<<dim3(N1_ / 128, M_ / 128), 256, 0, stream>>>(x, Wqkv, qs, qb, ks, kb, qkv);
    transpose_v<<<dim3(P_ / 64, B_ * H_), 256, 0, stream>>>(qkv, v_t);
    attn_mfma<<<dim3(P_ / 64, B_ * H_), 256, 0, stream>>>(qkv, v_t, attn_sb, stats);
    gemm_out_mfma<<<dim3(D_ / 128, M_ / 128), 256, 0, stream>>>(attn_sb, stats, osc, ob, Wout, bout, out);
}

// Round 10
// 281.007 us; speedup vs baseline: 1.0441x; 1.0441x over previous
//
#include <hip/hip_runtime.h>
#include <hip/hip_bf16.h>

// Problem constants (B=2, P=2048, D=768, H=12, hd=64)
#define B_  2
#define P_  2048
#define D_  768
#define H_  12
#define HD_ 64
#define M_  (B_ * P_)   // 4096
#define N1_ (3 * D_)    // 2304

typedef __attribute__((ext_vector_type(8))) short short8;   // 8 bf16 (4 VGPRs)
typedef __attribute__((ext_vector_type(4))) float f32x4;    // MFMA accumulator
typedef unsigned short ushort;

__device__ __forceinline__ ushort f2bf(float f) {
    unsigned u = __float_as_uint(f);
    u += 0x7fffu + ((u >> 16) & 1u);   // RNE
    return (ushort)(u >> 16);
}

// ===========================================================================
// Kernel 1: qkv = x @ W_qkv (bf16 MFMA) + fused per-head QK-LayerNorm.
// (unchanged from R7/R8)
// ===========================================================================
__global__ __launch_bounds__(256) void gemm_qkv_mfma(
        const float* __restrict__ x, const float* __restrict__ w,
        const float* __restrict__ qs, const float* __restrict__ qb,
        const float* __restrict__ ks, const float* __restrict__ kb,
        ushort* __restrict__ qkv) {
    __shared__ __align__(16) ushort As[128][40];
    __shared__ __align__(16) ushort Bs[128][40];

    const int tid  = threadIdx.x;
    const int lane = tid & 63;
    const int wv   = tid >> 6;
    const int quad = lane >> 4;
    const int col  = lane & 15;
    const int wr   = (wv >> 1) * 64;
    const int wc   = (wv & 1) * 64;
    const int rowBase = blockIdx.y * 128;
    const int colBase = blockIdx.x * 128;

    const int nB    = tid & 127;
    const int khalf = tid >> 7;
    const int am    = tid >> 3, ac4 = tid & 7;

    float4 apre[4];
    float  bpre[16];

    auto load_tile = [&](int kt) {
        const int k0 = kt * 32;
#pragma unroll
        for (int i = 0; i < 4; i++)
            apre[i] = *(const float4*)(x + (size_t)(rowBase + am + i * 32) * D_ + k0 + ac4 * 4);
#pragma unroll
        for (int j = 0; j < 16; j++)
            bpre[j] = w[(size_t)(k0 + khalf * 16 + j) * N1_ + colBase + nB];
    };

    f32x4 acc[4][4];
#pragma unroll
    for (int i = 0; i < 4; i++)
#pragma unroll
        for (int j = 0; j < 4; j++) acc[i][j] = (f32x4){0.f, 0.f, 0.f, 0.f};

    load_tile(0);
    const int NT = D_ / 32;
    for (int kt = 0; kt < NT; kt++) {
        __syncthreads();
#pragma unroll
        for (int i = 0; i < 4; i++) {
            ushort u4[4] = {f2bf(apre[i].x), f2bf(apre[i].y), f2bf(apre[i].z), f2bf(apre[i].w)};
            *(uint2*)&As[am + i * 32][ac4 * 4] = *(uint2*)u4;
        }
        {
            ushort us[16];
#pragma unroll
            for (int j = 0; j < 16; j++) us[j] = f2bf(bpre[j]);
            *(short8*)&Bs[nB][khalf * 16]     = *(short8*)&us[0];
            *(short8*)&Bs[nB][khalf * 16 + 8] = *(short8*)&us[8];
        }
        __syncthreads();
        if (kt + 1 < NT) load_tile(kt + 1);

        short8 af[4], bf[4];
#pragma unroll
        for (int mt = 0; mt < 4; mt++) af[mt] = *(const short8*)&As[wr + mt * 16 + col][quad * 8];
#pragma unroll
        for (int nt = 0; nt < 4; nt++) bf[nt] = *(const short8*)&Bs[wc + nt * 16 + col][quad * 8];
#pragma unroll
        for (int mt = 0; mt < 4; mt++)
#pragma unroll
            for (int nt = 0; nt < 4; nt++)
                acc[mt][nt] = __builtin_amdgcn_mfma_f32_16x16x32_bf16(af[mt], bf[nt], acc[mt][nt], 0, 0, 0);
    }

    const int comp = colBase / D_;
    const int rem  = colBase + wc - comp * D_;
    const int h    = rem >> 6;
    float sc4[4] = {0, 0, 0, 0}, bi4[4] = {0, 0, 0, 0};
    if (comp == 0) {
#pragma unroll
        for (int nt = 0; nt < 4; nt++) { sc4[nt] = qs[nt * 16 + col]; bi4[nt] = qb[nt * 16 + col]; }
    } else if (comp == 1) {
#pragma unroll
        for (int nt = 0; nt < 4; nt++) { sc4[nt] = ks[nt * 16 + col]; bi4[nt] = kb[nt * 16 + col]; }
    }

#pragma unroll
    for (int mt = 0; mt < 4; mt++) {
#pragma unroll
        for (int r = 0; r < 4; r++) {
            int m  = rowBase + wr + mt * 16 + quad * 4 + r;
            int bb = m >> 11;
            int p  = m & 2047;
            float v0 = acc[mt][0][r], v1 = acc[mt][1][r], v2 = acc[mt][2][r], v3 = acc[mt][3][r];
            if (comp < 2) {
                float s = v0 + v1 + v2 + v3;
#pragma unroll
                for (int off = 1; off < 16; off <<= 1) s += __shfl_xor(s, off, 64);
                float mean = s * (1.0f / 64.0f);
                float d0 = v0 - mean, d1 = v1 - mean, d2 = v2 - mean, d3 = v3 - mean;
                float sq = d0 * d0 + d1 * d1 + d2 * d2 + d3 * d3;
#pragma unroll
                for (int off = 1; off < 16; off <<= 1) sq += __shfl_xor(sq, off, 64);
                float inv = rsqrtf(sq * (1.0f / 64.0f) + 1e-6f);
                v0 = d0 * inv * sc4[0] + bi4[0];
                v1 = d1 * inv * sc4[1] + bi4[1];
                v2 = d2 * inv * sc4[2] + bi4[2];
                v3 = d3 * inv * sc4[3] + bi4[3];
                if (comp == 0) { v0 *= 0.125f; v1 *= 0.125f; v2 *= 0.125f; v3 *= 0.125f; }
            }
            size_t base = ((((size_t)comp * B_ + bb) * H_ + h) * P_ + p) * HD_;
            qkv[base +  0 + col] = f2bf(v0);
            qkv[base + 16 + col] = f2bf(v1);
            qkv[base + 32 + col] = f2bf(v2);
            qkv[base + 48 + col] = f2bf(v3);
        }
    }
}

// ===========================================================================
// Kernel 2: flash attention, split-K over keys (split index = kernel arg).
// R8 loop structure; clamped unnormalized softmax -> partials ADD across
// splits. No Qs tile (Q frags direct to regs): LDS 27.6 KB -> 5 blocks/CU.
// ===========================================================================
__global__ __launch_bounds__(256) void attn_split(const ushort* __restrict__ qkv,
                                                  float* __restrict__ opart,   // [bh][p][64]
                                                  float* __restrict__ lpart,   // [bh*P]
                                                  int s) {
    const int p0 = blockIdx.x * 64;
    const int bh = blockIdx.y;
    const int b  = bh / H_, h = bh % H_;
    const int tid  = threadIdx.x;
    const int lane = tid & 63;
    const int wv   = tid >> 6;
    const int quad = lane >> 4;
    const int col  = lane & 15;

    __shared__ __align__(16) ushort Ks[64][72];
    __shared__ __align__(16) ushort Vs[64][72];      // [dim][key] transposed
    __shared__ __align__(16) ushort Ps[4][16][72];

    const size_t hs = (size_t)P_ * HD_;
    const ushort* qg = qkv + ((size_t)(0 * B_ + b) * H_ + h) * hs + (size_t)p0 * HD_;
    const ushort* kg = qkv + ((size_t)(1 * B_ + b) * H_ + h) * hs + (size_t)s * (P_ / 2) * HD_;
    const ushort* vg = qkv + ((size_t)(2 * B_ + b) * H_ + h) * hs + (size_t)s * (P_ / 2) * HD_;

    // Q fragments straight from global (one-time; 16B-aligned, row stride 128B)
    short8 aq0 = *(const short8*)(qg + (size_t)(wv * 16 + col) * HD_ + quad * 8);
    short8 aq1 = *(const short8*)(qg + (size_t)(wv * 16 + col) * HD_ + 32 + quad * 8);

    float lrow[4] = {0.f, 0.f, 0.f, 0.f};
    f32x4 oacc[4];
#pragma unroll
    for (int nt = 0; nt < 4; nt++) oacc[nt] = (f32x4){0.f, 0.f, 0.f, 0.f};

    const int kr = tid >> 3, kc8 = tid & 7;
    const int vd = tid & 63,  vkh = tid >> 6;

    uint4  kpre[2];
    ushort vpre[16];
    auto load_tile = [&](int kt) {
        const ushort* kg_t = kg + (size_t)kt * 64 * HD_;
        const ushort* vg_t = vg + (size_t)kt * 64 * HD_;
        kpre[0] = *(const uint4*)(kg_t + (size_t)kr * HD_ + kc8 * 8);
        kpre[1] = *(const uint4*)(kg_t + (size_t)(kr + 32) * HD_ + kc8 * 8);
#pragma unroll
        for (int j = 0; j < 16; j++)
            vpre[j] = vg_t[(size_t)(vkh * 16 + j) * HD_ + vd];
    };

    load_tile(0);
    const int NT = (P_ / 2) / 64;    // 16 tiles per split
    for (int kt = 0; kt < NT; kt++) {
        __syncthreads();
        *(uint4*)&Ks[kr][kc8 * 8]      = kpre[0];
        *(uint4*)&Ks[kr + 32][kc8 * 8] = kpre[1];
        *(short8*)&Vs[vd][vkh * 16]     = *(short8*)&vpre[0];
        *(short8*)&Vs[vd][vkh * 16 + 8] = *(short8*)&vpre[8];
        __syncthreads();
        if (kt + 1 < NT) load_tile(kt + 1);

        // S = Q @ K^T
        f32x4 sc[4];
#pragma unroll
        for (int nt = 0; nt < 4; nt++) {
            sc[nt] = (f32x4){0.f, 0.f, 0.f, 0.f};
            short8 b0 = *(const short8*)&Ks[nt * 16 + col][0 * 32 + quad * 8];
            short8 b1 = *(const short8*)&Ks[nt * 16 + col][1 * 32 + quad * 8];
            sc[nt] = __builtin_amdgcn_mfma_f32_16x16x32_bf16(aq0, b0, sc[nt], 0, 0, 0);
            sc[nt] = __builtin_amdgcn_mfma_f32_16x16x32_bf16(aq1, b1, sc[nt], 0, 0, 0);
        }

        // Unnormalized clamped softmax
#pragma unroll
        for (int r = 0; r < 4; r++) {
#pragma unroll
            for (int nt = 0; nt < 4; nt++) {
                float p = __expf(fminf(sc[nt][r], 60.f));
                lrow[r] += p;
                Ps[wv][quad * 4 + r][nt * 16 + col] = f2bf(p);
            }
        }
        // No barrier: Ps is per-wave; DS ops are wave-in-order.

        // O += P @ V
#pragma unroll
        for (int nt = 0; nt < 4; nt++) {
#pragma unroll
            for (int ks2 = 0; ks2 < 2; ks2++) {
                short8 a   = *(const short8*)&Ps[wv][col][ks2 * 32 + quad * 8];
                short8 bfr = *(const short8*)&Vs[nt * 16 + col][ks2 * 32 + quad * 8];
                oacc[nt] = __builtin_amdgcn_mfma_f32_16x16x32_bf16(a, bfr, oacc[nt], 0, 0, 0);
            }
        }
    }

    // Row-sum reduction (within quad)
#pragma unroll
    for (int r = 0; r < 4; r++) {
#pragma unroll
        for (int off = 1; off < 16; off <<= 1) lrow[r] += __shfl_xor(lrow[r], off, 64);
    }

    // Partial writeback: [bh][p][64] contiguous rows.
#pragma unroll
    for (int r = 0; r < 4; r++) {
        int q = p0 + wv * 16 + quad * 4 + r;
        float* dst = opart + ((size_t)bh * P_ + q) * HD_;
#pragma unroll
        for (int nt = 0; nt < 4; nt++) dst[nt * 16 + col] = oacc[nt][r];
        if (col == 0) lpart[(size_t)bh * P_ + q] = lrow[r];
    }
}

// ===========================================================================
// Kernel 3: combine: io = (o0 + io) / (l0 + l1), remapped [bh][p][64] ->
// [b][p][h*64+d]. Each thread owns disjoint read/write elements only within
// its own (bh,p,d4) — but read idx != write idx across threads, so stage the
// value first and use a grid where each block handles BOTH layouts of the
// same rows? Simpler & safe: write to a different buffer region is not
// available — instead note read addr (bh,p,d) and write addr (b,p,h,d) are
// bijective permutations of the same buffer; a block may write a location
// another block hasn't read yet. To avoid the race, combine writes into
// opart0 (ws) instead, and ln_o reads opart0 with the [bh][p][64] layout
// remapping applied at read time. => combine is pure elementwise in place.
// ===========================================================================
__global__ __launch_bounds__(256) void combine_split(
        float* __restrict__ o0, const float* __restrict__ o1,
        const float* __restrict__ l0, const float* __restrict__ l1) {
    const int flat = blockIdx.x * 256 + threadIdx.x;   // float4 index
    const int row  = flat >> 4;                        // bh*P + p
    size_t pidx = (size_t)flat * 4;
    float4 a = *(const float4*)(o0 + pidx);
    float4 c = *(const float4*)(o1 + pidx);
    float invl = 1.0f / (l0[row] + l1[row]);
    float4 o = {(a.x + c.x) * invl, (a.y + c.y) * invl,
                (a.z + c.z) * invl, (a.w + c.w) * invl};
    *(float4*)(o0 + pidx) = o;
}

// ===========================================================================
// Kernel 4: LayerNorm over D=768 reading the [bh][p][64] layout (head-major)
// and writing ln_buf in row-major [b][p][D] bf16.
// Thread tid covers dims {tid, tid+256, tid+512} of row (b,p):
// dim d -> head h=d>>6, source a[((b*H+h)*P+p)*64 + (d&63)].
// ===========================================================================
__global__ __launch_bounds__(256) void ln_o(const float* __restrict__ a,
                                            ushort* __restrict__ lnb,
                                            const float* __restrict__ osc,
                                            const float* __restrict__ ob) {
    __shared__ float red[4];
    __shared__ float red2[4];
    const int row = blockIdx.x;          // b*P + p
    const int b   = row >> 11;
    const int p   = row & (P_ - 1);
    const int tid = threadIdx.x;

    auto src = [&](int d) {
        int h = d >> 6;
        return a[(((size_t)(b * H_ + h)) * P_ + p) * HD_ + (d & 63)];
    };
    float v0 = src(tid);
    float v1 = src(tid + 256);
    float v2 = src(tid + 512);
    float s = v0 + v1 + v2;
#pragma unroll
    for (int o = 32; o > 0; o >>= 1) s += __shfl_xor(s, o, 64);
    if ((tid & 63) == 0) red[tid >> 6] = s;
    __syncthreads();
    float mean = (red[0] + red[1] + red[2] + red[3]) * (1.0f / 768.0f);
    float d0 = v0 - mean, d1 = v1 - mean, d2 = v2 - mean;
    float sq = d0 * d0 + d1 * d1 + d2 * d2;
#pragma unroll
    for (int o = 32; o > 0; o >>= 1) sq += __shfl_xor(sq, o, 64);
    if ((tid & 63) == 0) red2[tid >> 6] = sq;
    __syncthreads();
    float var = (red2[0] + red2[1] + red2[2] + red2[3]) * (1.0f / 768.0f);
    float inv = rsqrtf(var + 1e-6f);
    const size_t base = (size_t)row * D_;
    lnb[base + tid]       = f2bf(d0 * inv * osc[tid]       + ob[tid]);
    lnb[base + tid + 256] = f2bf(d1 * inv * osc[tid + 256] + ob[tid + 256]);
    lnb[base + tid + 512] = f2bf(d2 * inv * osc[tid + 512] + ob[tid + 512]);
}

// ===========================================================================
// Kernel 5: out = ln_buf(bf16) @ W_out + b_out, fp32 output. (unchanged R8)
// ===========================================================================
__global__ __launch_bounds__(256) void gemm_out_mfma(
        const ushort* __restrict__ a, const float* __restrict__ w,
        const float* __restrict__ bias, float* __restrict__ out) {
    __shared__ __align__(16) ushort As[128][40];
    __shared__ __align__(16) ushort Bs[128][40];

    const int tid  = threadIdx.x;
    const int lane = tid & 63;
    const int wv   = tid >> 6;
    const int quad = lane >> 4;
    const int col  = lane & 15;
    const int wr   = (wv >> 1) * 64;
    const int wc   = (wv & 1) * 64;
    const int rowBase = blockIdx.y * 128;
    const int colBase = blockIdx.x * 128;

    const int nB    = tid & 127;
    const int khalf = tid >> 7;
    const int am    = tid >> 2, ac8 = tid & 3;

    uint4 apre[2];
    float bpre[16];
    auto load_tile = [&](int kt) {
        const int k0 = kt * 32;
        apre[0] = *(const uint4*)(a + (size_t)(rowBase + am) * D_ + k0 + ac8 * 8);
        apre[1] = *(const uint4*)(a + (size_t)(rowBase + am + 64) * D_ + k0 + ac8 * 8);
#pragma unroll
        for (int j = 0; j < 16; j++)
            bpre[j] = w[(size_t)(k0 + khalf * 16 + j) * D_ + colBase + nB];
    };

    f32x4 acc[4][4];
#pragma unroll
    for (int i = 0; i < 4; i++)
#pragma unroll
        for (int j = 0; j < 4; j++) acc[i][j] = (f32x4){0.f, 0.f, 0.f, 0.f};

    load_tile(0);
    const int NT = D_ / 32;
    for (int kt = 0; kt < NT; kt++) {
        __syncthreads();
        *(uint4*)&As[am][ac8 * 8]      = apre[0];
        *(uint4*)&As[am + 64][ac8 * 8] = apre[1];
        {
            ushort us[16];
#pragma unroll
            for (int j = 0; j < 16; j++) us[j] = f2bf(bpre[j]);
            *(short8*)&Bs[nB][khalf * 16]     = *(short8*)&us[0];
            *(short8*)&Bs[nB][khalf * 16 + 8] = *(short8*)&us[8];
        }
        __syncthreads();
        if (kt + 1 < NT) load_tile(kt + 1);

        short8 af[4], bf[4];
#pragma unroll
        for (int mt = 0; mt < 4; mt++) af[mt] = *(const short8*)&As[wr + mt * 16 + col][quad * 8];
#pragma unroll
        for (int nt = 0; nt < 4; nt++) bf[nt] = *(const short8*)&Bs[wc + nt * 16 + col][quad * 8];
#pragma unroll
        for (int mt = 0; mt < 4; mt++)
#pragma unroll
            for (int nt = 0; nt < 4; nt++)
                acc[mt][nt] = __builtin_amdgcn_mfma_f32_16x16x32_bf16(af[mt], bf[nt], acc[mt][nt], 0, 0, 0);
    }

    float b4[4];
#pragma unroll
    for (int nt = 0; nt < 4; nt++) b4[nt] = bias[colBase + wc + nt * 16 + col];
#pragma unroll
    for (int mt = 0; mt < 4; mt++) {
#pragma unroll
        for (int r = 0; r < 4; r++) {
            int m = rowBase + wr + mt * 16 + quad * 4 + r;
            float* dst = out + (size_t)m * D_ + colBase + wc;
#pragma unroll
            for (int nt = 0; nt < 4; nt++)
                dst[nt * 16 + col] = acc[mt][nt][r] + b4[nt];
        }
    }
}

// ---------------------------------------------------------------------------
extern "C" void kernel_launch(void* const* d_in, const int* in_sizes, int n_in,
                              void* d_out, int out_size, void* d_ws, size_t ws_size,
                              hipStream_t stream) {
    const float* x    = (const float*)d_in[0];
    const float* Wqkv = (const float*)d_in[1];
    const float* qs   = (const float*)d_in[2];
    const float* qb   = (const float*)d_in[3];
    const float* ks   = (const float*)d_in[4];
    const float* kb   = (const float*)d_in[5];
    const float* osc  = (const float*)d_in[6];
    const float* ob   = (const float*)d_in[7];
    const float* Wout = (const float*)d_in[8];
    const float* bout = (const float*)d_in[9];
    float* out = (float*)d_out;

    // Workspace (31.9 MB): qkv bf16 18.9MB | opart0 fp32 12.6MB | l0,l1 0.4MB
    // d_out holds opart1 during attention (fp32, exactly B*P*D elements).
    ushort* qkv    = (ushort*)d_ws;
    float*  opart0 = (float*)(qkv + (size_t)3 * B_ * H_ * P_ * HD_);
    float*  l0     = opart0 + (size_t)B_ * H_ * P_ * HD_;
    float*  l1     = l0 + (size_t)B_ * H_ * P_;
    float*  opart1 = out;
    ushort* ln_buf = qkv;   // overlays dead q-region after attention

    gemm_qkv_mfma<<<dim3(N1_ / 128, M_ / 128), 256, 0, stream>>>(x, Wqkv, qs, qb, ks, kb, qkv);
    attn_split<<<dim3(P_ / 64, B_ * H_), 256, 0, stream>>>(qkv, opart0, l0, 0);
    attn_split<<<dim3(P_ / 64, B_ * H_), 256, 0, stream>>>(qkv, opart1, l1, 1);
    combine_split<<<dim3((B_ * H_ * P_ * HD_ / 4) / 256), 256, 0, stream>>>(opart0, opart1, l0, l1);
    ln_o<<<dim3(M_), 256, 0, stream>>>(opart0, ln_buf, osc, ob);
    gemm_out_mfma<<<dim3(D_ / 128, M_ / 128), 256, 0, stream>>>(ln_buf, Wout, bout, out);
}

// Round 11
// 248.268 us; speedup vs baseline: 1.1818x; 1.1319x over previous
//
#include <hip/hip_runtime.h>
#include <hip/hip_bf16.h>

// Problem constants (B=2, P=2048, D=768, H=12, hd=64)
#define B_  2
#define P_  2048
#define D_  768
#define H_  12
#define HD_ 64
#define M_  (B_ * P_)   // 4096
#define N1_ (3 * D_)    // 2304

typedef __attribute__((ext_vector_type(8))) short short8;   // 8 bf16 (4 VGPRs)
typedef __attribute__((ext_vector_type(4))) float f32x4;    // MFMA accumulator
typedef unsigned short ushort;

__device__ __forceinline__ ushort f2bf(float f) {
    unsigned u = __float_as_uint(f);
    u += 0x7fffu + ((u >> 16) & 1u);   // RNE
    return (ushort)(u >> 16);
}

// ===========================================================================
// Kernel 1: qkv = x @ W_qkv (bf16 MFMA) + fused per-head QK-LayerNorm.
// 128x128 tile, BK=32, now 512 threads / 8 waves (4x2): wave = 32 rows x 64
// cols -> LN epilogue still sees a full head per wave. Register prefetch.
// ===========================================================================
__global__ __launch_bounds__(512) void gemm_qkv_mfma(
        const float* __restrict__ x, const float* __restrict__ w,
        const float* __restrict__ qs, const float* __restrict__ qb,
        const float* __restrict__ ks, const float* __restrict__ kb,
        ushort* __restrict__ qkv) {
    __shared__ __align__(16) ushort As[128][40];
    __shared__ __align__(16) ushort Bs[128][40];

    const int tid  = threadIdx.x;
    const int lane = tid & 63;
    const int wv   = tid >> 6;            // 0..7
    const int quad = lane >> 4;
    const int col  = lane & 15;
    const int wr   = (wv >> 1) * 32;      // wave row offset (4 groups)
    const int wc   = (wv & 1) * 64;       // wave col offset (2 groups)
    const int rowBase = blockIdx.y * 128;
    const int colBase = blockIdx.x * 128;

    const int am0 = tid >> 3, ac4 = tid & 7;   // A staging: rows am0, am0+64
    const int nB  = tid & 127, kq = tid >> 7;  // B staging: rows kq*8..+7

    float4 apre[2];
    float  bpre[8];
    auto load_tile = [&](int kt) {
        const int k0 = kt * 32;
        apre[0] = *(const float4*)(x + (size_t)(rowBase + am0) * D_ + k0 + ac4 * 4);
        apre[1] = *(const float4*)(x + (size_t)(rowBase + am0 + 64) * D_ + k0 + ac4 * 4);
#pragma unroll
        for (int j = 0; j < 8; j++)
            bpre[j] = w[(size_t)(k0 + kq * 8 + j) * N1_ + colBase + nB];
    };

    f32x4 acc[2][4];
#pragma unroll
    for (int i = 0; i < 2; i++)
#pragma unroll
        for (int j = 0; j < 4; j++) acc[i][j] = (f32x4){0.f, 0.f, 0.f, 0.f};

    load_tile(0);
    const int NT = D_ / 32;
    for (int kt = 0; kt < NT; kt++) {
        __syncthreads();
        {
            ushort u0[4] = {f2bf(apre[0].x), f2bf(apre[0].y), f2bf(apre[0].z), f2bf(apre[0].w)};
            ushort u1[4] = {f2bf(apre[1].x), f2bf(apre[1].y), f2bf(apre[1].z), f2bf(apre[1].w)};
            *(uint2*)&As[am0][ac4 * 4]      = *(uint2*)u0;
            *(uint2*)&As[am0 + 64][ac4 * 4] = *(uint2*)u1;
            ushort us[8];
#pragma unroll
            for (int j = 0; j < 8; j++) us[j] = f2bf(bpre[j]);
            *(short8*)&Bs[nB][kq * 8] = *(short8*)&us[0];
        }
        __syncthreads();
        if (kt + 1 < NT) load_tile(kt + 1);

        short8 af[2], bf[4];
#pragma unroll
        for (int mt = 0; mt < 2; mt++) af[mt] = *(const short8*)&As[wr + mt * 16 + col][quad * 8];
#pragma unroll
        for (int nt = 0; nt < 4; nt++) bf[nt] = *(const short8*)&Bs[wc + nt * 16 + col][quad * 8];
#pragma unroll
        for (int mt = 0; mt < 2; mt++)
#pragma unroll
            for (int nt = 0; nt < 4; nt++)
                acc[mt][nt] = __builtin_amdgcn_mfma_f32_16x16x32_bf16(af[mt], bf[nt], acc[mt][nt], 0, 0, 0);
    }

    const int comp = colBase / D_;             // 128 | 768 -> block-uniform
    const int rem  = colBase + wc - comp * D_;
    const int h    = rem >> 6;
    float sc4[4] = {0, 0, 0, 0}, bi4[4] = {0, 0, 0, 0};
    if (comp == 0) {
#pragma unroll
        for (int nt = 0; nt < 4; nt++) { sc4[nt] = qs[nt * 16 + col]; bi4[nt] = qb[nt * 16 + col]; }
    } else if (comp == 1) {
#pragma unroll
        for (int nt = 0; nt < 4; nt++) { sc4[nt] = ks[nt * 16 + col]; bi4[nt] = kb[nt * 16 + col]; }
    }

#pragma unroll
    for (int mt = 0; mt < 2; mt++) {
#pragma unroll
        for (int r = 0; r < 4; r++) {
            int m  = rowBase + wr + mt * 16 + quad * 4 + r;
            int bb = m >> 11;
            int p  = m & 2047;
            float v0 = acc[mt][0][r], v1 = acc[mt][1][r], v2 = acc[mt][2][r], v3 = acc[mt][3][r];
            if (comp < 2) {
                float s = v0 + v1 + v2 + v3;
#pragma unroll
                for (int off = 1; off < 16; off <<= 1) s += __shfl_xor(s, off, 64);
                float mean = s * (1.0f / 64.0f);
                float d0 = v0 - mean, d1 = v1 - mean, d2 = v2 - mean, d3 = v3 - mean;
                float sq = d0 * d0 + d1 * d1 + d2 * d2 + d3 * d3;
#pragma unroll
                for (int off = 1; off < 16; off <<= 1) sq += __shfl_xor(sq, off, 64);
                float inv = rsqrtf(sq * (1.0f / 64.0f) + 1e-6f);
                v0 = d0 * inv * sc4[0] + bi4[0];
                v1 = d1 * inv * sc4[1] + bi4[1];
                v2 = d2 * inv * sc4[2] + bi4[2];
                v3 = d3 * inv * sc4[3] + bi4[3];
                if (comp == 0) { v0 *= 0.125f; v1 *= 0.125f; v2 *= 0.125f; v3 *= 0.125f; }
            }
            size_t base = ((((size_t)comp * B_ + bb) * H_ + h) * P_ + p) * HD_;
            qkv[base +  0 + col] = f2bf(v0);
            qkv[base + 16 + col] = f2bf(v1);
            qkv[base + 32 + col] = f2bf(v2);
            qkv[base + 48 + col] = f2bf(v3);
        }
    }
}

// ===========================================================================
// Kernel 2: flash attention, split-K over keys, SINGLE dispatch (grid z=2).
// R8 loop; clamped unnormalized softmax -> partials add across splits.
// No Qs tile: LDS 27.6 KB. 1536 blocks concurrent.
// ===========================================================================
__global__ __launch_bounds__(256) void attn_split(const ushort* __restrict__ qkv,
                                                  float* __restrict__ o0,
                                                  float* __restrict__ o1,
                                                  float* __restrict__ l0,
                                                  float* __restrict__ l1) {
    const int p0 = blockIdx.x * 64;
    const int bh = blockIdx.y;
    const int s  = blockIdx.z;
    const int b  = bh / H_, h = bh % H_;
    float* opart = s ? o1 : o0;
    float* lpart = s ? l1 : l0;
    const int tid  = threadIdx.x;
    const int lane = tid & 63;
    const int wv   = tid >> 6;
    const int quad = lane >> 4;
    const int col  = lane & 15;

    __shared__ __align__(16) ushort Ks[64][72];
    __shared__ __align__(16) ushort Vs[64][72];      // [dim][key] transposed
    __shared__ __align__(16) ushort Ps[4][16][72];

    const size_t hs = (size_t)P_ * HD_;
    const ushort* qg = qkv + ((size_t)(0 * B_ + b) * H_ + h) * hs + (size_t)p0 * HD_;
    const ushort* kg = qkv + ((size_t)(1 * B_ + b) * H_ + h) * hs + (size_t)s * (P_ / 2) * HD_;
    const ushort* vg = qkv + ((size_t)(2 * B_ + b) * H_ + h) * hs + (size_t)s * (P_ / 2) * HD_;

    short8 aq0 = *(const short8*)(qg + (size_t)(wv * 16 + col) * HD_ + quad * 8);
    short8 aq1 = *(const short8*)(qg + (size_t)(wv * 16 + col) * HD_ + 32 + quad * 8);

    float lrow[4] = {0.f, 0.f, 0.f, 0.f};
    f32x4 oacc[4];
#pragma unroll
    for (int nt = 0; nt < 4; nt++) oacc[nt] = (f32x4){0.f, 0.f, 0.f, 0.f};

    const int kr = tid >> 3, kc8 = tid & 7;
    const int vd = tid & 63,  vkh = tid >> 6;

    uint4  kpre[2];
    ushort vpre[16];
    auto load_tile = [&](int kt) {
        const ushort* kg_t = kg + (size_t)kt * 64 * HD_;
        const ushort* vg_t = vg + (size_t)kt * 64 * HD_;
        kpre[0] = *(const uint4*)(kg_t + (size_t)kr * HD_ + kc8 * 8);
        kpre[1] = *(const uint4*)(kg_t + (size_t)(kr + 32) * HD_ + kc8 * 8);
#pragma unroll
        for (int j = 0; j < 16; j++)
            vpre[j] = vg_t[(size_t)(vkh * 16 + j) * HD_ + vd];
    };

    load_tile(0);
    const int NT = (P_ / 2) / 64;
    for (int kt = 0; kt < NT; kt++) {
        __syncthreads();
        *(uint4*)&Ks[kr][kc8 * 8]      = kpre[0];
        *(uint4*)&Ks[kr + 32][kc8 * 8] = kpre[1];
        *(short8*)&Vs[vd][vkh * 16]     = *(short8*)&vpre[0];
        *(short8*)&Vs[vd][vkh * 16 + 8] = *(short8*)&vpre[8];
        __syncthreads();
        if (kt + 1 < NT) load_tile(kt + 1);

        f32x4 sc[4];
#pragma unroll
        for (int nt = 0; nt < 4; nt++) {
            sc[nt] = (f32x4){0.f, 0.f, 0.f, 0.f};
            short8 b0 = *(const short8*)&Ks[nt * 16 + col][0 * 32 + quad * 8];
            short8 b1 = *(const short8*)&Ks[nt * 16 + col][1 * 32 + quad * 8];
            sc[nt] = __builtin_amdgcn_mfma_f32_16x16x32_bf16(aq0, b0, sc[nt], 0, 0, 0);
            sc[nt] = __builtin_amdgcn_mfma_f32_16x16x32_bf16(aq1, b1, sc[nt], 0, 0, 0);
        }

#pragma unroll
        for (int r = 0; r < 4; r++) {
#pragma unroll
            for (int nt = 0; nt < 4; nt++) {
                float p = __expf(fminf(sc[nt][r], 60.f));
                lrow[r] += p;
                Ps[wv][quad * 4 + r][nt * 16 + col] = f2bf(p);
            }
        }
        // No barrier: Ps is per-wave; DS ops are wave-in-order.

#pragma unroll
        for (int nt = 0; nt < 4; nt++) {
#pragma unroll
            for (int ks2 = 0; ks2 < 2; ks2++) {
                short8 a   = *(const short8*)&Ps[wv][col][ks2 * 32 + quad * 8];
                short8 bfr = *(const short8*)&Vs[nt * 16 + col][ks2 * 32 + quad * 8];
                oacc[nt] = __builtin_amdgcn_mfma_f32_16x16x32_bf16(a, bfr, oacc[nt], 0, 0, 0);
            }
        }
    }

#pragma unroll
    for (int r = 0; r < 4; r++) {
#pragma unroll
        for (int off = 1; off < 16; off <<= 1) lrow[r] += __shfl_xor(lrow[r], off, 64);
    }

#pragma unroll
    for (int r = 0; r < 4; r++) {
        int q = p0 + wv * 16 + quad * 4 + r;
        float* dst = opart + ((size_t)bh * P_ + q) * HD_;
#pragma unroll
        for (int nt = 0; nt < 4; nt++) dst[nt * 16 + col] = oacc[nt][r];
        if (col == 0) lpart[(size_t)bh * P_ + q] = lrow[r];
    }
}

// ===========================================================================
// Kernel 3: LayerNorm over D=768, fused split-combine: reads o0/o1 in
// [bh][p][64] layout, v = (o0+o1)/(l0+l1), LN, writes bf16 ln_buf [b][p][D].
// ===========================================================================
__global__ __launch_bounds__(256) void ln_o(const float* __restrict__ o0,
                                            const float* __restrict__ o1,
                                            const float* __restrict__ l0,
                                            const float* __restrict__ l1,
                                            ushort* __restrict__ lnb,
                                            const float* __restrict__ osc,
                                            const float* __restrict__ ob) {
    __shared__ float red[4];
    __shared__ float red2[4];
    const int row = blockIdx.x;          // b*P + p
    const int b   = row >> 11;
    const int p   = row & (P_ - 1);
    const int tid = threadIdx.x;

    auto src = [&](int d) {
        int h = d >> 6;
        size_t lr  = (size_t)(b * H_ + h) * P_ + p;
        size_t idx = lr * HD_ + (d & 63);
        return (o0[idx] + o1[idx]) / (l0[lr] + l1[lr]);
    };
    float v0 = src(tid);
    float v1 = src(tid + 256);
    float v2 = src(tid + 512);
    float s = v0 + v1 + v2;
#pragma unroll
    for (int o = 32; o > 0; o >>= 1) s += __shfl_xor(s, o, 64);
    if ((tid & 63) == 0) red[tid >> 6] = s;
    __syncthreads();
    float mean = (red[0] + red[1] + red[2] + red[3]) * (1.0f / 768.0f);
    float d0 = v0 - mean, d1 = v1 - mean, d2 = v2 - mean;
    float sq = d0 * d0 + d1 * d1 + d2 * d2;
#pragma unroll
    for (int o = 32; o > 0; o >>= 1) sq += __shfl_xor(sq, o, 64);
    if ((tid & 63) == 0) red2[tid >> 6] = sq;
    __syncthreads();
    float var = (red2[0] + red2[1] + red2[2] + red2[3]) * (1.0f / 768.0f);
    float inv = rsqrtf(var + 1e-6f);
    const size_t base = (size_t)row * D_;
    lnb[base + tid]       = f2bf(d0 * inv * osc[tid]       + ob[tid]);
    lnb[base + tid + 256] = f2bf(d1 * inv * osc[tid + 256] + ob[tid + 256]);
    lnb[base + tid + 512] = f2bf(d2 * inv * osc[tid + 512] + ob[tid + 512]);
}

// ===========================================================================
// Kernel 4: out = ln_buf(bf16) @ W_out + b_out, fp32 output.
// Retiled 64x64 (grid 12x64 = 768 blocks = 3/CU). 4 waves of 32x32, BK=32.
// ===========================================================================
__global__ __launch_bounds__(256) void gemm_out_mfma(
        const ushort* __restrict__ a, const float* __restrict__ w,
        const float* __restrict__ bias, float* __restrict__ out) {
    __shared__ __align__(16) ushort As[64][40];
    __shared__ __align__(16) ushort Bs[64][40];

    const int tid  = threadIdx.x;
    const int lane = tid & 63;
    const int wv   = tid >> 6;
    const int quad = lane >> 4;
    const int col  = lane & 15;
    const int wr   = (wv >> 1) * 32;
    const int wc   = (wv & 1) * 32;
    const int rowBase = blockIdx.y * 64;
    const int colBase = blockIdx.x * 64;

    const int am  = tid >> 2, ac8 = tid & 3;   // A: 64 rows x 4 uint4-cols
    const int nB  = tid & 63, kq = tid >> 6;   // B: rows kq*8..+7, col nB

    uint4 apre;
    float bpre[8];
    auto load_tile = [&](int kt) {
        const int k0 = kt * 32;
        apre = *(const uint4*)(a + (size_t)(rowBase + am) * D_ + k0 + ac8 * 8);
#pragma unroll
        for (int j = 0; j < 8; j++)
            bpre[j] = w[(size_t)(k0 + kq * 8 + j) * D_ + colBase + nB];
    };

    f32x4 acc[2][2];
#pragma unroll
    for (int i = 0; i < 2; i++)
#pragma unroll
        for (int j = 0; j < 2; j++) acc[i][j] = (f32x4){0.f, 0.f, 0.f, 0.f};

    load_tile(0);
    const int NT = D_ / 32;
    for (int kt = 0; kt < NT; kt++) {
        __syncthreads();
        *(uint4*)&As[am][ac8 * 8] = apre;
        {
            ushort us[8];
#pragma unroll
            for (int j = 0; j < 8; j++) us[j] = f2bf(bpre[j]);
            *(short8*)&Bs[nB][kq * 8] = *(short8*)&us[0];
        }
        __syncthreads();
        if (kt + 1 < NT) load_tile(kt + 1);

        short8 af[2], bf[2];
#pragma unroll
        for (int mt = 0; mt < 2; mt++) af[mt] = *(const short8*)&As[wr + mt * 16 + col][quad * 8];
#pragma unroll
        for (int nt = 0; nt < 2; nt++) bf[nt] = *(const short8*)&Bs[wc + nt * 16 + col][quad * 8];
#pragma unroll
        for (int mt = 0; mt < 2; mt++)
#pragma unroll
            for (int nt = 0; nt < 2; nt++)
                acc[mt][nt] = __builtin_amdgcn_mfma_f32_16x16x32_bf16(af[mt], bf[nt], acc[mt][nt], 0, 0, 0);
    }

    float b2[2];
#pragma unroll
    for (int nt = 0; nt < 2; nt++) b2[nt] = bias[colBase + wc + nt * 16 + col];
#pragma unroll
    for (int mt = 0; mt < 2; mt++) {
#pragma unroll
        for (int r = 0; r < 4; r++) {
            int m = rowBase + wr + mt * 16 + quad * 4 + r;
            float* dst = out + (size_t)m * D_ + colBase + wc;
#pragma unroll
            for (int nt = 0; nt < 2; nt++)
                dst[nt * 16 + col] = acc[mt][nt][r] + b2[nt];
        }
    }
}

// ---------------------------------------------------------------------------
extern "C" void kernel_launch(void* const* d_in, const int* in_sizes, int n_in,
                              void* d_out, int out_size, void* d_ws, size_t ws_size,
                              hipStream_t stream) {
    const float* x    = (const float*)d_in[0];
    const float* Wqkv = (const float*)d_in[1];
    const float* qs   = (const float*)d_in[2];
    const float* qb   = (const float*)d_in[3];
    const float* ks   = (const float*)d_in[4];
    const float* kb   = (const float*)d_in[5];
    const float* osc  = (const float*)d_in[6];
    const float* ob   = (const float*)d_in[7];
    const float* Wout = (const float*)d_in[8];
    const float* bout = (const float*)d_in[9];
    float* out = (float*)d_out;

    // Workspace (31.9 MB): qkv bf16 18.9MB | opart0 fp32 12.6MB | l0,l1 0.4MB
    // d_out holds opart1 during attention (fp32, exactly B*P*D elements).
    ushort* qkv    = (ushort*)d_ws;
    float*  opart0 = (float*)(qkv + (size_t)3 * B_ * H_ * P_ * HD_);
    float*  l0     = opart0 + (size_t)B_ * H_ * P_ * HD_;
    float*  l1     = l0 + (size_t)B_ * H_ * P_;
    float*  opart1 = out;
    ushort* ln_buf = qkv;   // overlays dead q-region after attention

    gemm_qkv_mfma<<<dim3(N1_ / 128, M_ / 128), 512, 0, stream>>>(x, Wqkv, qs, qb, ks, kb, qkv);
    attn_split<<<dim3(P_ / 64, B_ * H_, 2), 256, 0, stream>>>(qkv, opart0, opart1, l0, l1);
    ln_o<<<dim3(M_), 256, 0, stream>>>(opart0, opart1, l0, l1, ln_buf, osc, ob);
    gemm_out_mfma<<<dim3(D_ / 64, M_ / 64), 256, 0, stream>>>(ln_buf, Wout, bout, out);
}

// Round 14
// 207.977 us; speedup vs baseline: 1.4108x; 1.1937x over previous
//
#include <hip/hip_runtime.h>
#include <hip/hip_bf16.h>

// Problem constants (B=2, P=2048, D=768, H=12, hd=64)
#define B_  2
#define P_  2048
#define D_  768
#define H_  12
#define HD_ 64
#define M_  (B_ * P_)   // 4096
#define N1_ (3 * D_)    // 2304

typedef __attribute__((ext_vector_type(8))) short short8;    // 8 bf16 (4 VGPRs)
typedef __attribute__((ext_vector_type(4))) float f32x4;     // 16x16 MFMA acc
typedef __attribute__((ext_vector_type(16))) float f32x16;   // 32x32 MFMA acc
typedef unsigned short ushort;

__device__ __forceinline__ ushort f2bf(float f) {
    unsigned u = __float_as_uint(f);
    u += 0x7fffu + ((u >> 16) & 1u);   // RNE
    return (ushort)(u >> 16);
}

// ===========================================================================
// Kernel 1: qkv = x @ W_qkv (bf16 MFMA) + fused per-head QK-LayerNorm.
// 128x128 tile, BK=32, 512 threads / 8 waves (4x2). (unchanged from R11)
// ===========================================================================
__global__ __launch_bounds__(512) void gemm_qkv_mfma(
        const float* __restrict__ x, const float* __restrict__ w,
        const float* __restrict__ qs, const float* __restrict__ qb,
        const float* __restrict__ ks, const float* __restrict__ kb,
        ushort* __restrict__ qkv) {
    __shared__ __align__(16) ushort As[128][40];
    __shared__ __align__(16) ushort Bs[128][40];

    const int tid  = threadIdx.x;
    const int lane = tid & 63;
    const int wv   = tid >> 6;            // 0..7
    const int quad = lane >> 4;
    const int col  = lane & 15;
    const int wr   = (wv >> 1) * 32;
    const int wc   = (wv & 1) * 64;
    const int rowBase = blockIdx.y * 128;
    const int colBase = blockIdx.x * 128;

    const int am0 = tid >> 3, ac4 = tid & 7;
    const int nB  = tid & 127, kq = tid >> 7;

    float4 apre[2];
    float  bpre[8];
    auto load_tile = [&](int kt) {
        const int k0 = kt * 32;
        apre[0] = *(const float4*)(x + (size_t)(rowBase + am0) * D_ + k0 + ac4 * 4);
        apre[1] = *(const float4*)(x + (size_t)(rowBase + am0 + 64) * D_ + k0 + ac4 * 4);
#pragma unroll
        for (int j = 0; j < 8; j++)
            bpre[j] = w[(size_t)(k0 + kq * 8 + j) * N1_ + colBase + nB];
    };

    f32x4 acc[2][4];
#pragma unroll
    for (int i = 0; i < 2; i++)
#pragma unroll
        for (int j = 0; j < 4; j++) acc[i][j] = (f32x4){0.f, 0.f, 0.f, 0.f};

    load_tile(0);
    const int NT = D_ / 32;
    for (int kt = 0; kt < NT; kt++) {
        __syncthreads();
        {
            ushort u0[4] = {f2bf(apre[0].x), f2bf(apre[0].y), f2bf(apre[0].z), f2bf(apre[0].w)};
            ushort u1[4] = {f2bf(apre[1].x), f2bf(apre[1].y), f2bf(apre[1].z), f2bf(apre[1].w)};
            *(uint2*)&As[am0][ac4 * 4]      = *(uint2*)u0;
            *(uint2*)&As[am0 + 64][ac4 * 4] = *(uint2*)u1;
            ushort us[8];
#pragma unroll
            for (int j = 0; j < 8; j++) us[j] = f2bf(bpre[j]);
            *(short8*)&Bs[nB][kq * 8] = *(short8*)&us[0];
        }
        __syncthreads();
        if (kt + 1 < NT) load_tile(kt + 1);

        short8 af[2], bf[4];
#pragma unroll
        for (int mt = 0; mt < 2; mt++) af[mt] = *(const short8*)&As[wr + mt * 16 + col][quad * 8];
#pragma unroll
        for (int nt = 0; nt < 4; nt++) bf[nt] = *(const short8*)&Bs[wc + nt * 16 + col][quad * 8];
#pragma unroll
        for (int mt = 0; mt < 2; mt++)
#pragma unroll
            for (int nt = 0; nt < 4; nt++)
                acc[mt][nt] = __builtin_amdgcn_mfma_f32_16x16x32_bf16(af[mt], bf[nt], acc[mt][nt], 0, 0, 0);
    }

    const int comp = colBase / D_;
    const int rem  = colBase + wc - comp * D_;
    const int h    = rem >> 6;
    float sc4[4] = {0, 0, 0, 0}, bi4[4] = {0, 0, 0, 0};
    if (comp == 0) {
#pragma unroll
        for (int nt = 0; nt < 4; nt++) { sc4[nt] = qs[nt * 16 + col]; bi4[nt] = qb[nt * 16 + col]; }
    } else if (comp == 1) {
#pragma unroll
        for (int nt = 0; nt < 4; nt++) { sc4[nt] = ks[nt * 16 + col]; bi4[nt] = kb[nt * 16 + col]; }
    }

#pragma unroll
    for (int mt = 0; mt < 2; mt++) {
#pragma unroll
        for (int r = 0; r < 4; r++) {
            int m  = rowBase + wr + mt * 16 + quad * 4 + r;
            int bb = m >> 11;
            int p  = m & 2047;
            float v0 = acc[mt][0][r], v1 = acc[mt][1][r], v2 = acc[mt][2][r], v3 = acc[mt][3][r];
            if (comp < 2) {
                float s = v0 + v1 + v2 + v3;
#pragma unroll
                for (int off = 1; off < 16; off <<= 1) s += __shfl_xor(s, off, 64);
                float mean = s * (1.0f / 64.0f);
                float d0 = v0 - mean, d1 = v1 - mean, d2 = v2 - mean, d3 = v3 - mean;
                float sq = d0 * d0 + d1 * d1 + d2 * d2 + d3 * d3;
#pragma unroll
                for (int off = 1; off < 16; off <<= 1) sq += __shfl_xor(sq, off, 64);
                float inv = rsqrtf(sq * (1.0f / 64.0f) + 1e-6f);
                v0 = d0 * inv * sc4[0] + bi4[0];
                v1 = d1 * inv * sc4[1] + bi4[1];
                v2 = d2 * inv * sc4[2] + bi4[2];
                v3 = d3 * inv * sc4[3] + bi4[3];
                if (comp == 0) { v0 *= 0.125f; v1 *= 0.125f; v2 *= 0.125f; v3 *= 0.125f; }
            }
            size_t base = ((((size_t)comp * B_ + bb) * H_ + h) * P_ + p) * HD_;
            qkv[base +  0 + col] = f2bf(v0);
            qkv[base + 16 + col] = f2bf(v1);
            qkv[base + 32 + col] = f2bf(v2);
            qkv[base + 48 + col] = f2bf(v3);
        }
    }
}

// ===========================================================================
// Kernel 2: flash attention, 32x32x16 MFMA, split-K (grid z=2).
// Block = 128 q rows, 4 waves; wave owns 32 q. Clamped unnormalized softmax.
// C/D layout (verified m74/m101): col=lane&31, row=(reg&3)+8*(reg>>2)+4*(lane>>5).
// A[m=lane&31][k=8*(lane>>5)+j]; B[k=8*(lane>>5)+j][n=lane&31] — confirmed by
// R12/R13 producing bit-identical outputs across shapes.
// Writeback: RAW partial O (normalization happens ONCE in ln_o — R12/R13's
// double-normalization bug fixed) via per-wave LDS transpose for
// 256B-contiguous row stores.
// ===========================================================================
__global__ __launch_bounds__(256) void attn_split(const ushort* __restrict__ qkv,
                                                  float* __restrict__ o0,
                                                  float* __restrict__ o1,
                                                  float* __restrict__ l0,
                                                  float* __restrict__ l1) {
    const int p0 = blockIdx.x * 128;
    const int bh = blockIdx.y;
    const int s  = blockIdx.z;
    const int b  = bh / H_, h = bh % H_;
    float* opart = s ? o1 : o0;
    float* lpart = s ? l1 : l0;
    const int tid  = threadIdx.x;
    const int lane = tid & 63;
    const int wv   = tid >> 6;
    const int half = lane >> 5;     // 0/1
    const int n32  = lane & 31;

    __shared__ __align__(16) ushort Ks[64][72];
    __shared__ __align__(16) ushort Vs[64][72];      // [dim][key] transposed
    __shared__ __align__(16) ushort Ps[4][32][72];   // per-wave [q][key]; reused as fp32 [32][36]

    const size_t hs = (size_t)P_ * HD_;
    const ushort* qg = qkv + ((size_t)(0 * B_ + b) * H_ + h) * hs + (size_t)(p0 + wv * 32) * HD_;
    const ushort* kg = qkv + ((size_t)(1 * B_ + b) * H_ + h) * hs + (size_t)s * (P_ / 2) * HD_;
    const ushort* vg = qkv + ((size_t)(2 * B_ + b) * H_ + h) * hs + (size_t)s * (P_ / 2) * HD_;

    // Q A-fragments for 4 K=16 steps, direct from global.
    short8 aq[4];
#pragma unroll
    for (int ks2 = 0; ks2 < 4; ks2++)
        aq[ks2] = *(const short8*)(qg + (size_t)n32 * HD_ + ks2 * 16 + half * 8);

    float lrow[16];
#pragma unroll
    for (int r = 0; r < 16; r++) lrow[r] = 0.f;
    f32x16 oacc[2];
#pragma unroll
    for (int nt = 0; nt < 2; nt++)
#pragma unroll
        for (int r = 0; r < 16; r++) oacc[nt][r] = 0.f;

    const int kr = tid >> 3, kc8 = tid & 7;
    const int vd = tid & 63,  vkh = tid >> 6;

    uint4  kpre[2];
    ushort vpre[16];
    auto load_tile = [&](int kt) {
        const ushort* kg_t = kg + (size_t)kt * 64 * HD_;
        const ushort* vg_t = vg + (size_t)kt * 64 * HD_;
        kpre[0] = *(const uint4*)(kg_t + (size_t)kr * HD_ + kc8 * 8);
        kpre[1] = *(const uint4*)(kg_t + (size_t)(kr + 32) * HD_ + kc8 * 8);
#pragma unroll
        for (int j = 0; j < 16; j++)
            vpre[j] = vg_t[(size_t)(vkh * 16 + j) * HD_ + vd];
    };

    load_tile(0);
    const int NT = (P_ / 2) / 64;    // 16 tiles per split
    for (int kt = 0; kt < NT; kt++) {
        __syncthreads();
        *(uint4*)&Ks[kr][kc8 * 8]      = kpre[0];
        *(uint4*)&Ks[kr + 32][kc8 * 8] = kpre[1];
        *(short8*)&Vs[vd][vkh * 16]     = *(short8*)&vpre[0];
        *(short8*)&Vs[vd][vkh * 16 + 8] = *(short8*)&vpre[8];
        __syncthreads();
        if (kt + 1 < NT) load_tile(kt + 1);

        // S = Q(32x64) @ K^T(64keys x 64): 2 key-tiles x 4 k-steps.
        // C: row=q=(reg&3)+8*(reg>>2)+4*half, col=key=nt*32+n32.
        f32x16 sc[2];
#pragma unroll
        for (int nt = 0; nt < 2; nt++) {
#pragma unroll
            for (int r = 0; r < 16; r++) sc[nt][r] = 0.f;
#pragma unroll
            for (int ks2 = 0; ks2 < 4; ks2++) {
                short8 kb2 = *(const short8*)&Ks[nt * 32 + n32][ks2 * 16 + half * 8];
                sc[nt] = __builtin_amdgcn_mfma_f32_32x32x16_bf16(aq[ks2], kb2, sc[nt], 0, 0, 0);
            }
        }

        // Clamped unnormalized softmax; Ps[q][key] per-wave.
#pragma unroll
        for (int reg = 0; reg < 16; reg++) {
            int row = (reg & 3) + 8 * (reg >> 2) + 4 * half;
#pragma unroll
            for (int nt = 0; nt < 2; nt++) {
                float p = __expf(fminf(sc[nt][reg], 60.f));
                lrow[reg] += p;
                Ps[wv][row][nt * 32 + n32] = f2bf(p);
            }
        }
        // No barrier: Ps is per-wave; DS ops are wave-in-order.

        // O(32q x 64d) += P(32q x 64key) @ V(64key x 64d).
        // A = Ps[q][key]; B = Vs[dim][key] read as B[k=key][n=dim].
#pragma unroll
        for (int kp = 0; kp < 4; kp++) {
            short8 pa = *(const short8*)&Ps[wv][n32][kp * 16 + half * 8];
#pragma unroll
            for (int nt = 0; nt < 2; nt++) {
                short8 vb = *(const short8*)&Vs[nt * 32 + n32][kp * 16 + half * 8];
                oacc[nt] = __builtin_amdgcn_mfma_f32_32x32x16_bf16(pa, vb, oacc[nt], 0, 0, 0);
            }
        }
    }

    // Row-sum reduction over the 32 cols (lanes within each half).
#pragma unroll
    for (int reg = 0; reg < 16; reg++) {
#pragma unroll
        for (int off = 1; off < 32; off <<= 1)
            lrow[reg] += __shfl_xor(lrow[reg], off, 64);
    }

    // l writes: lane 0 of each half writes its 16 rows (compile-time reg idx).
    if (n32 == 0) {
#pragma unroll
        for (int reg = 0; reg < 16; reg++) {
            int row = (reg & 3) + 8 * (reg >> 2) + 4 * half;
            lpart[(size_t)bh * P_ + p0 + wv * 32 + row] = lrow[reg];
        }
    }

    // RAW partial-O writeback via per-wave LDS transpose (Ps[wv] as [32][36] f32).
    float* Psf = (float*)&Ps[wv][0][0];
#pragma unroll
    for (int nt = 0; nt < 2; nt++) {
#pragma unroll
        for (int reg = 0; reg < 16; reg++) {
            int row = (reg & 3) + 8 * (reg >> 2) + 4 * half;
            Psf[row * 36 + n32] = oacc[nt][reg];
        }
        // In-wave DS ordering: writes above complete before reads below.
#pragma unroll
        for (int i = 0; i < 4; i++) {
            int ql = i * 8 + (lane >> 3);
            int c4 = lane & 7;
            float4 v = *(const float4*)&Psf[ql * 36 + c4 * 4];
            *(float4*)(opart + ((size_t)bh * P_ + p0 + wv * 32 + ql) * HD_ + nt * 32 + c4 * 4) = v;
        }
    }
}

// ===========================================================================
// Kernel 3: LayerNorm over D=768, fused split-combine: v = (o0+o1)/(l0+l1).
// (unchanged from R11 — sole owner of normalization)
// ===========================================================================
__global__ __launch_bounds__(256) void ln_o(const float* __restrict__ o0,
                                            const float* __restrict__ o1,
                                            const float* __restrict__ l0,
                                            const float* __restrict__ l1,
                                            ushort* __restrict__ lnb,
                                            const float* __restrict__ osc,
                                            const float* __restrict__ ob) {
    __shared__ float red[4];
    __shared__ float red2[4];
    const int row = blockIdx.x;          // b*P + p
    const int b   = row >> 11;
    const int p   = row & (P_ - 1);
    const int tid = threadIdx.x;

    auto src = [&](int d) {
        int h = d >> 6;
        size_t lr  = (size_t)(b * H_ + h) * P_ + p;
        size_t idx = lr * HD_ + (d & 63);
        return (o0[idx] + o1[idx]) / (l0[lr] + l1[lr]);
    };
    float v0 = src(tid);
    float v1 = src(tid + 256);
    float v2 = src(tid + 512);
    float s = v0 + v1 + v2;
#pragma unroll
    for (int o = 32; o > 0; o >>= 1) s += __shfl_xor(s, o, 64);
    if ((tid & 63) == 0) red[tid >> 6] = s;
    __syncthreads();
    float mean = (red[0] + red[1] + red[2] + red[3]) * (1.0f / 768.0f);
    float d0 = v0 - mean, d1 = v1 - mean, d2 = v2 - mean;
    float sq = d0 * d0 + d1 * d1 + d2 * d2;
#pragma unroll
    for (int o = 32; o > 0; o >>= 1) sq += __shfl_xor(sq, o, 64);
    if ((tid & 63) == 0) red2[tid >> 6] = sq;
    __syncthreads();
    float var = (red2[0] + red2[1] + red2[2] + red2[3]) * (1.0f / 768.0f);
    float inv = rsqrtf(var + 1e-6f);
    const size_t base = (size_t)row * D_;
    lnb[base + tid]       = f2bf(d0 * inv * osc[tid]       + ob[tid]);
    lnb[base + tid + 256] = f2bf(d1 * inv * osc[tid + 256] + ob[tid + 256]);
    lnb[base + tid + 512] = f2bf(d2 * inv * osc[tid + 512] + ob[tid + 512]);
}

// ===========================================================================
// Kernel 4: out = ln_buf(bf16) @ W_out + b_out. 64x64 tile. (unchanged R11)
// ===========================================================================
__global__ __launch_bounds__(256) void gemm_out_mfma(
        const ushort* __restrict__ a, const float* __restrict__ w,
        const float* __restrict__ bias, float* __restrict__ out) {
    __shared__ __align__(16) ushort As[64][40];
    __shared__ __align__(16) ushort Bs[64][40];

    const int tid  = threadIdx.x;
    const int lane = tid & 63;
    const int wv   = tid >> 6;
    const int quad = lane >> 4;
    const int col  = lane & 15;
    const int wr   = (wv >> 1) * 32;
    const int wc   = (wv & 1) * 32;
    const int rowBase = blockIdx.y * 64;
    const int colBase = blockIdx.x * 64;

    const int am  = tid >> 2, ac8 = tid & 3;
    const int nB  = tid & 63, kq = tid >> 6;

    uint4 apre;
    float bpre[8];
    auto load_tile = [&](int kt) {
        const int k0 = kt * 32;
        apre = *(const uint4*)(a + (size_t)(rowBase + am) * D_ + k0 + ac8 * 8);
#pragma unroll
        for (int j = 0; j < 8; j++)
            bpre[j] = w[(size_t)(k0 + kq * 8 + j) * D_ + colBase + nB];
    };

    f32x4 acc[2][2];
#pragma unroll
    for (int i = 0; i < 2; i++)
#pragma unroll
        for (int j = 0; j < 2; j++) acc[i][j] = (f32x4){0.f, 0.f, 0.f, 0.f};

    load_tile(0);
    const int NT = D_ / 32;
    for (int kt = 0; kt < NT; kt++) {
        __syncthreads();
        *(uint4*)&As[am][ac8 * 8] = apre;
        {
            ushort us[8];
#pragma unroll
            for (int j = 0; j < 8; j++) us[j] = f2bf(bpre[j]);
            *(short8*)&Bs[nB][kq * 8] = *(short8*)&us[0];
        }
        __syncthreads();
        if (kt + 1 < NT) load_tile(kt + 1);

        short8 af[2], bf[2];
#pragma unroll
        for (int mt = 0; mt < 2; mt++) af[mt] = *(const short8*)&As[wr + mt * 16 + col][quad * 8];
#pragma unroll
        for (int nt = 0; nt < 2; nt++) bf[nt] = *(const short8*)&Bs[wc + nt * 16 + col][quad * 8];
#pragma unroll
        for (int mt = 0; mt < 2; mt++)
#pragma unroll
            for (int nt = 0; nt < 2; nt++)
                acc[mt][nt] = __builtin_amdgcn_mfma_f32_16x16x32_bf16(af[mt], bf[nt], acc[mt][nt], 0, 0, 0);
    }

    float b2[2];
#pragma unroll
    for (int nt = 0; nt < 2; nt++) b2[nt] = bias[colBase + wc + nt * 16 + col];
#pragma unroll
    for (int mt = 0; mt < 2; mt++) {
#pragma unroll
        for (int r = 0; r < 4; r++) {
            int m = rowBase + wr + mt * 16 + quad * 4 + r;
            float* dst = out + (size_t)m * D_ + colBase + wc;
#pragma unroll
            for (int nt = 0; nt < 2; nt++)
                dst[nt * 16 + col] = acc[mt][nt][r] + b2[nt];
        }
    }
}

// ---------------------------------------------------------------------------
extern "C" void kernel_launch(void* const* d_in, const int* in_sizes, int n_in,
                              void* d_out, int out_size, void* d_ws, size_t ws_size,
                              hipStream_t stream) {
    const float* x    = (const float*)d_in[0];
    const float* Wqkv = (const float*)d_in[1];
    const float* qs   = (const float*)d_in[2];
    const float* qb   = (const float*)d_in[3];
    const float* ks   = (const float*)d_in[4];
    const float* kb   = (const float*)d_in[5];
    const float* osc  = (const float*)d_in[6];
    const float* ob   = (const float*)d_in[7];
    const float* Wout = (const float*)d_in[8];
    const float* bout = (const float*)d_in[9];
    float* out = (float*)d_out;

    // Workspace (31.9 MB): qkv bf16 18.9MB | opart0 fp32 12.6MB | l0,l1 0.4MB
    // d_out holds opart1 during attention (fp32, exactly B*P*D elements).
    ushort* qkv    = (ushort*)d_ws;
    float*  opart0 = (float*)(qkv + (size_t)3 * B_ * H_ * P_ * HD_);
    float*  l0     = opart0 + (size_t)B_ * H_ * P_ * HD_;
    float*  l1     = l0 + (size_t)B_ * H_ * P_;
    float*  opart1 = out;
    ushort* ln_buf = qkv;   // overlays dead q-region after attention

    gemm_qkv_mfma<<<dim3(N1_ / 128, M_ / 128), 512, 0, stream>>>(x, Wqkv, qs, qb, ks, kb, qkv);
    attn_split<<<dim3(P_ / 128, B_ * H_, 2), 256, 0, stream>>>(qkv, opart0, opart1, l0, l1);
    ln_o<<<dim3(M_), 256, 0, stream>>>(opart0, opart1, l0, l1, ln_buf, osc, ob);
    gemm_out_mfma<<<dim3(D_ / 64, M_ / 64), 256, 0, stream>>>(ln_buf, Wout, bout, out);
}